// Round 23
// baseline (116.860 us; speedup 1.0000x reference)
//
#include <hip/hip_runtime.h>
#include <cstdint>

typedef _Float16 half_t;
using half8 = __attribute__((ext_vector_type(8))) half_t;
using half4 = __attribute__((ext_vector_type(4))) half_t;
using f32x4 = __attribute__((ext_vector_type(4))) float;
using f32x16 = __attribute__((ext_vector_type(16))) float;

#define LSEQ 2048
#define DM   1024
#define NH   16
#define DK   64

// ---------- helpers ----------
__device__ inline void gload_lds16(const void* g, void* l) {
    __builtin_amdgcn_global_load_lds(
        (const __attribute__((address_space(1))) uint32_t*)g,
        (__attribute__((address_space(3))) uint32_t*)l, 16, 0, 0);
}

__device__ inline uint32_t pk2(float a, float b) {
    auto h = __builtin_amdgcn_cvt_pkrtz(a, b);   // v_cvt_pkrtz_f16_f32
    return __builtin_bit_cast(uint32_t, h);
}

__device__ inline float ex2(float x) { return __builtin_amdgcn_exp2f(x); }  // raw v_exp_f32

// ---------- 1. convert fp32 -> fp16 (q,k,v,W*) + RoPE table (fused) ----------
__global__ __launch_bounds__(256) void cvt_kernel(
    const float* __restrict__ q, const float* __restrict__ k, const float* __restrict__ v,
    const float* __restrict__ wq, const float* __restrict__ wk,
    const float* __restrict__ wv, const float* __restrict__ wo,
    half_t* __restrict__ dst, float* __restrict__ cosT, float* __restrict__ sinT)
{
    if (blockIdx.x >= 16384) {   // rope table: [d1=0..31][pos=0..2047]
        int tid = (blockIdx.x - 16384) * 256 + threadIdx.x;   // 65536
        int j = tid >> 11;
        int pos = tid & 2047;
        float invf = powf(10000.0f, -(float)j / 32.0f);
        float a = (float)pos * invf;
        cosT[tid] = cosf(a);
        sinT[tid] = sinf(a);
        return;
    }
    long tid = (long)blockIdx.x * 256 + threadIdx.x;
    long e = tid * 4;
    const float* src;
    long off;
    if (e < 12582912L) {
        int a = (int)(e >> 22);
        src = (a == 0) ? q : (a == 1) ? k : v;
        off = e & 4194303L;
    } else {
        long ew = e - 12582912L;
        int w = (int)(ew >> 20);
        src = (w == 0) ? wq : (w == 1) ? wk : (w == 2) ? wv : wo;
        off = ew & 1048575L;
    }
    float4 x = *(const float4*)(src + off);
    half4 o;
    o[0] = (half_t)x.x; o[1] = (half_t)x.y; o[2] = (half_t)x.z; o[3] = (half_t)x.w;
    *(half4*)(dst + e) = o;
}

// ---------- 3a. fused QKV projection GEMM, 8 waves, chunk-swizzled LDS ----------
__global__ __launch_bounds__(512, 6) void qkv_gemm(
    const half_t* __restrict__ XH, const half_t* __restrict__ WH,
    const float* __restrict__ bq, const float* __restrict__ bk, const float* __restrict__ bv,
    half_t* __restrict__ QF, half_t* __restrict__ KF, half_t* __restrict__ VF,
    const float* __restrict__ cosT, const float* __restrict__ sinT)
{
    __shared__ alignas(16) unsigned short sA[2][128 * 32];
    __shared__ alignas(16) unsigned short sB[2][128 * 32];
    const int mode = blockIdx.z;
    const half_t* A  = XH + (long)mode * 4194304L;
    const half_t* Bw = WH + (long)mode * 1048576L;
    const float* bias = (mode == 0) ? bq : (mode == 1) ? bk : bv;

    const int tid = threadIdx.x;
    const int lane = tid & 63, wid = tid >> 6;      // 0..7
    const int g = lane >> 4, c = lane & 15;
    const int wr = wid >> 1, wc = wid & 1;          // 4 x 2 wave grid
    const int row0 = blockIdx.y * 128, col0 = blockIdx.x * 128;

    f32x4 acc[2][4] = {};
    const int srow = lane >> 2;
    const int scol = ((lane & 3) ^ ((lane >> 3) & 3)) * 8;   // inverse-swizzled source chunk
    const int kx   = (g ^ ((c >> 1) & 3)) * 8;               // swizzled read chunk

    auto stage = [&](int buf, int k0) {
        int r = wid * 16;
        gload_lds16(A  + (long)(row0 + r + srow) * DM + k0 + scol, &sA[buf][r * 32]);
        gload_lds16(Bw + (long)(col0 + r + srow) * DM + k0 + scol, &sB[buf][r * 32]);
    };

    stage(0, 0);
    __syncthreads();
    int cur = 0;
#pragma unroll 1
    for (int k0 = 0; k0 < DM; k0 += 32) {
        if (k0 + 32 < DM) stage(cur ^ 1, k0 + 32);   // prefetch next K-tile
        half8 af[2], bf[4];
#pragma unroll
        for (int m = 0; m < 2; ++m)
            af[m] = *(const half8*)&sA[cur][(wr * 32 + m * 16 + c) * 32 + kx];
#pragma unroll
        for (int n = 0; n < 4; ++n)
            bf[n] = *(const half8*)&sB[cur][(wc * 64 + n * 16 + c) * 32 + kx];
#pragma unroll
        for (int m = 0; m < 2; ++m)
#pragma unroll
            for (int n = 0; n < 4; ++n)
                acc[m][n] = __builtin_amdgcn_mfma_f32_16x16x32_f16(af[m], bf[n], acc[m][n], 0, 0, 0);
        __syncthreads();
        cur ^= 1;
    }

    if (mode == 2) {
        const int h = blockIdx.x * 2 + wc;
#pragma unroll
        for (int n = 0; n < 4; ++n) {
            int col = col0 + wc * 64 + n * 16 + c;
            int d = n * 16 + c;
            float bvv = bias[col];
#pragma unroll
            for (int m = 0; m < 2; ++m) {
                int row = row0 + wr * 32 + m * 16 + g * 4;   // +r, r=0..3
                int b = row >> 11, pos = row & 2047;
                int bh = b * NH + h;
                long idx = (((((long)bh * 32 + (pos >> 6)) * 2 + (d >> 5)) * 4
                             + ((pos >> 4) & 3)) * 64
                            + (((pos >> 3) & 1) * 32 + (d & 31))) * 8 + (pos & 7);
                half4 o;
#pragma unroll
                for (int r = 0; r < 4; ++r) o[r] = (half_t)(acc[m][n][r] + bvv);
                *(half4*)(VF + idx) = o;
            }
        }
    } else {
        const float SC = (mode == 0) ? 0.125f * 1.44269504f : 1.0f;
        half_t* OF = (mode == 0) ? QF : KF;
#pragma unroll
        for (int np = 0; np < 2; ++np) {
            int col1 = col0 + wc * 64 + np * 16 + c;
            int h = col1 >> 6;
            int d1 = np * 16 + c;          // 0..31
            float b1 = bias[col1], b2 = bias[col1 + 32];
            const float* Cp = cosT + d1 * 2048;
            const float* Sp = sinT + d1 * 2048;
#pragma unroll
            for (int m = 0; m < 2; ++m) {
                int row = row0 + wr * 32 + m * 16 + g * 4;
                int pos0 = row & 2047;
                float4 cv4 = *(const float4*)(Cp + pos0);
                float4 sv4 = *(const float4*)(Sp + pos0);
#pragma unroll
                for (int r = 0; r < 4; ++r) {
                    int pos = pos0 + r;
                    int b = (row + r) >> 11;
                    int bh = b * NH + h;
                    float cv = ((const float*)&cv4)[r];
                    float sv = ((const float*)&sv4)[r];
                    float x1 = acc[m][np][r] + b1;
                    float x2 = acc[m][np + 2][r] + b2;
                    long kbase = ((long)(bh * 64 + (pos >> 5)) * 4) * 512
                               + ((c >> 3) * 32 + (pos & 31)) * 8 + (c & 7);
                    OF[kbase + (long)np * 512]       = (half_t)((x1 * cv - x2 * sv) * SC);
                    OF[kbase + (long)(np + 2) * 512] = (half_t)((x2 * cv + x1 * sv) * SC);
                }
            }
        }
    }
}

// ---------- 3b. output projection GEMM: 128x64 tiles, 512 blocks, 8 waves ----------
__global__ __launch_bounds__(512, 4) void out_gemm(
    const half_t* __restrict__ A, const half_t* __restrict__ Bw,
    const float* __restrict__ bias, float* __restrict__ o32)
{
    __shared__ alignas(16) unsigned short sA[2][128 * 32];   // 16 KB
    __shared__ alignas(16) unsigned short sB[2][64 * 32];    // 8 KB
    const int tid = threadIdx.x;
    const int lane = tid & 63, wid = tid >> 6;   // 0..7
    const int g = lane >> 4, c = lane & 15;
    const int wr = wid >> 1, wc = wid & 1;       // 4 x 2 wave grid, wave tile 32x32
    const int row0 = blockIdx.y * 128, col0 = blockIdx.x * 64;

    f32x4 acc[2][2] = {};
    const int srow = lane >> 2;
    const int scol = ((lane & 3) ^ ((lane >> 3) & 3)) * 8;
    const int kx   = (g ^ ((c >> 1) & 3)) * 8;

    auto stage = [&](int buf, int k0) {
        int rA = wid * 16;
        gload_lds16(A + (long)(row0 + rA + srow) * DM + k0 + scol, &sA[buf][rA * 32]);
        if (wid < 4) {
            int rB = wid * 16;
            gload_lds16(Bw + (long)(col0 + rB + srow) * DM + k0 + scol, &sB[buf][rB * 32]);
        }
    };

    stage(0, 0);
    __syncthreads();
    int cur = 0;
#pragma unroll 1
    for (int k0 = 0; k0 < DM; k0 += 32) {
        if (k0 + 32 < DM) stage(cur ^ 1, k0 + 32);
        half8 af[2], bf[2];
#pragma unroll
        for (int m = 0; m < 2; ++m)
            af[m] = *(const half8*)&sA[cur][(wr * 32 + m * 16 + c) * 32 + kx];
#pragma unroll
        for (int n = 0; n < 2; ++n)
            bf[n] = *(const half8*)&sB[cur][(wc * 32 + n * 16 + c) * 32 + kx];
#pragma unroll
        for (int m = 0; m < 2; ++m)
#pragma unroll
            for (int n = 0; n < 2; ++n)
                acc[m][n] = __builtin_amdgcn_mfma_f32_16x16x32_f16(af[m], bf[n], acc[m][n], 0, 0, 0);
        __syncthreads();
        cur ^= 1;
    }
#pragma unroll
    for (int n = 0; n < 2; ++n) {
        int col = col0 + wc * 32 + n * 16 + c;
        float bv = bias[col];
#pragma unroll
        for (int m = 0; m < 2; ++m)
#pragma unroll
            for (int r = 0; r < 4; ++r) {
                int row = row0 + wr * 32 + m * 16 + g * 4 + r;
                o32[(long)row * DM + col] = acc[m][n][r] + bv;
            }
    }
}

// ---------- 4. causal flash attention: balanced split-K ----------
// Block = (tile t, bh), big-first; 8 waves: sub = row slice (4 x 32 rows),
// grp = key parity (even/odd 64-key blocks of the staged 128). Every wave
// computes every staged iteration -> block wall = t+1 iters, all waves busy.
// 2-way merge per row-slice through reused LDS at the end.
// lp[] folded to 8 registers (f32 sum reassociation; saves rescale VALU+VGPR).
__global__ __launch_bounds__(512, 3) void attn_k(
    const half_t* __restrict__ QF, const half_t* __restrict__ KF,
    const half_t* __restrict__ VF, half_t* __restrict__ AO)
{
    __shared__ half_t sK[2 * 8192];   // 32 KB: 2 buf x 128 keys x 64 d
    __shared__ half_t sV[2 * 8192];   // 32 KB

    const int tid = threadIdx.x;
    const int lane = tid & 63, wid = tid >> 6;   // 0..7
    const int t  = 15 - (blockIdx.x >> 5);       // big tiles first
    const int bh = blockIdx.x & 31;
    const int qc = lane & 31, hi = lane >> 5;
    const int b = bh >> 4, h = bh & 15;
    const int lo8 = lane * 8;
    const int sub = wid & 3, grp = wid >> 2;

    const half_t* QU = QF + (long)bh * 131072;
    const half_t* KU = KF + (long)bh * 131072;
    const half_t* VU = VF + (long)bh * 131072;

    const int qb = 128 * t + 32 * sub;
    const int kend = qb + 32;                 // keys needed by this row slice

    half8 qf[4];
#pragma unroll
    for (int dc = 0; dc < 4; ++dc)
        qf[dc] = *(const half8*)(QU + (qb >> 5) * 2048 + dc * 512 + lo8);

    f32x16 acc[2] = {};
    float lp[8];
#pragma unroll
    for (int r = 0; r < 8; ++r) lp[r] = 0.0f;
    float m = -INFINITY;

    union PB { uint32_t u[4]; half8 h8; };

    auto stage = [&](int buf, int k0) {       // stage 128 keys of K and V
#pragma unroll
        for (int rr = 0; rr < 2; ++rr) {
            gload_lds16(KU + (long)k0 * 64 + rr * 4096 + wid * 512 + lo8,
                        sK + buf * 8192 + rr * 4096 + wid * 512);
            gload_lds16(VU + (long)k0 * 64 + rr * 4096 + wid * 512 + lo8,
                        sV + buf * 8192 + rr * 4096 + wid * 512);
        }
    };

    const int nit = t + 1;                    // 128-key super-iterations
    stage(0, 0);
    __syncthreads();
    int cur = 0;
#pragma unroll 1
    for (int i = 0; i < nit; ++i) {
        if (i + 1 < nit) stage(cur ^ 1, 128 * (i + 1));
        const int base = 128 * i + grp * 64;  // this wave's 64-key block
        if (base < kend) {
            const half_t* bK = sK + cur * 8192 + grp * 4096;
            const half_t* bV = sV + cur * 8192 + grp * 4096;
            half8 kf0[4], kf1[4], vf[2][4];
#pragma unroll
            for (int dc = 0; dc < 4; ++dc) {
                kf0[dc] = *(const half8*)(bK + dc * 512 + lo8);
                kf1[dc] = *(const half8*)(bK + 2048 + dc * 512 + lo8);
            }
#pragma unroll
            for (int dt = 0; dt < 2; ++dt)
#pragma unroll
                for (int kc = 0; kc < 4; ++kc)
                    vf[dt][kc] = *(const half8*)(bV + (dt * 4 + kc) * 512 + lo8);

            // ---- QK^T ----
            f32x16 s0 = {}, s1 = {};
            __builtin_amdgcn_s_setprio(1);
#pragma unroll
            for (int dc = 0; dc < 4; ++dc) s0 = __builtin_amdgcn_mfma_f32_32x32x16_f16(kf0[dc], qf[dc], s0, 0, 0, 0);
#pragma unroll
            for (int dc = 0; dc < 4; ++dc) s1 = __builtin_amdgcn_mfma_f32_32x32x16_f16(kf1[dc], qf[dc], s1, 0, 0, 0);
            __builtin_amdgcn_s_setprio(0);

            if (base + 64 >= kend) {          // block containing the diagonal
                int qg = qb + qc;
#pragma unroll
                for (int r = 0; r < 16; ++r) {
                    int crow = (r & 3) + 8 * (r >> 2) + 4 * hi;
                    if (base + crow > qg)      s0[r] = -INFINITY;
                    if (base + 32 + crow > qg) s1[r] = -INFINITY;
                }
            }

            // ---- online softmax (defer-max; deferred l cross-reduce) ----
            float mx[8];
#pragma unroll
            for (int r = 0; r < 8; ++r)
                mx[r] = fmaxf(fmaxf(s0[r], s0[8 + r]), fmaxf(s1[r], s1[8 + r]));
#pragma unroll
            for (int st = 4; st >= 1; st >>= 1)
#pragma unroll
                for (int r = 0; r < 4; ++r)
                    if (r < st) mx[r] = fmaxf(mx[r], mx[r + st]);
            float pm = fmaxf(mx[0], __shfl_xor(mx[0], 32, 64));
            if (__any(pm > m + 8.0f)) {
                float mn = fmaxf(m, pm);
                float sc = ex2(m - mn);
#pragma unroll
                for (int r = 0; r < 16; ++r) { acc[0][r] *= sc; acc[1][r] *= sc; }
#pragma unroll
                for (int r = 0; r < 8; ++r) lp[r] *= sc;
                m = mn;
            }
#pragma unroll
            for (int r = 0; r < 16; ++r) {
                s0[r] = ex2(s0[r] - m);
                s1[r] = ex2(s1[r] - m);
            }
#pragma unroll
            for (int r = 0; r < 8; ++r)
                lp[r] += (s0[r] + s0[8 + r]) + (s1[r] + s1[8 + r]);

            // ---- pack P^T -> PV B-operand (cvt_pkrtz + permlane32_swap) ----
            uint32_t A0[8], A1[8];
#pragma unroll
            for (int i2 = 0; i2 < 8; ++i2) {
                A0[i2] = pk2(s0[2 * i2], s0[2 * i2 + 1]);
                A1[i2] = pk2(s1[2 * i2], s1[2 * i2 + 1]);
            }
            PB B00, B01, B10, B11;
            {
                auto r0 = __builtin_amdgcn_permlane32_swap(A0[0], A0[2], false, false);
                B00.u[0] = r0[0]; B00.u[2] = r0[1];
                auto r1 = __builtin_amdgcn_permlane32_swap(A0[1], A0[3], false, false);
                B00.u[1] = r1[0]; B00.u[3] = r1[1];
                auto r2 = __builtin_amdgcn_permlane32_swap(A0[4], A0[6], false, false);
                B01.u[0] = r2[0]; B01.u[2] = r2[1];
                auto r3 = __builtin_amdgcn_permlane32_swap(A0[5], A0[7], false, false);
                B01.u[1] = r3[0]; B01.u[3] = r3[1];
                auto r4 = __builtin_amdgcn_permlane32_swap(A1[0], A1[2], false, false);
                B10.u[0] = r4[0]; B10.u[2] = r4[1];
                auto r5 = __builtin_amdgcn_permlane32_swap(A1[1], A1[3], false, false);
                B10.u[1] = r5[0]; B10.u[3] = r5[1];
                auto r6 = __builtin_amdgcn_permlane32_swap(A1[4], A1[6], false, false);
                B11.u[0] = r6[0]; B11.u[2] = r6[1];
                auto r7 = __builtin_amdgcn_permlane32_swap(A1[5], A1[7], false, false);
                B11.u[1] = r7[0]; B11.u[3] = r7[1];
            }

            // ---- PV: O^T[d][q] += V^T * P ----
            __builtin_amdgcn_s_setprio(1);
#pragma unroll
            for (int dt = 0; dt < 2; ++dt) {
                acc[dt] = __builtin_amdgcn_mfma_f32_32x32x16_f16(vf[dt][0], B00.h8, acc[dt], 0, 0, 0);
                acc[dt] = __builtin_amdgcn_mfma_f32_32x32x16_f16(vf[dt][1], B01.h8, acc[dt], 0, 0, 0);
                acc[dt] = __builtin_amdgcn_mfma_f32_32x32x16_f16(vf[dt][2], B10.h8, acc[dt], 0, 0, 0);
                acc[dt] = __builtin_amdgcn_mfma_f32_32x32x16_f16(vf[dt][3], B11.h8, acc[dt], 0, 0, 0);
            }
            __builtin_amdgcn_s_setprio(0);
        }
        __syncthreads();
        cur ^= 1;
    }

    // ---- per-lane l partial ----
    float ls = lp[0];
#pragma unroll
    for (int r = 1; r < 8; ++r) ls += lp[r];

    // ---- 2-way split-K merge (grp1 -> LDS, grp0 finalizes) ----
    float* mA  = (float*)sK;    // 4 subs x 2048 f32 (32 KB)
    float* mML = (float*)sV;    // 4 subs x 128 f32
    if (grp == 1) {
        float* p = mA + sub * 2048;
#pragma unroll
        for (int dt = 0; dt < 2; ++dt)
#pragma unroll
            for (int r = 0; r < 16; ++r)
                p[(dt * 16 + r) * 64 + lane] = acc[dt][r];
        mML[sub * 128 + lane] = m;
        mML[sub * 128 + 64 + lane] = ls;
    }
    __syncthreads();
    if (grp == 0) {
        float m1  = mML[sub * 128 + lane];
        float ls1 = mML[sub * 128 + 64 + lane];
        float M = fmaxf(m, m1);
        float e0 = ex2(m - M), e1 = ex2(m1 - M);
        float lsM = ls * e0 + ls1 * e1;
        float l = lsM + __shfl_xor(lsM, 32, 64);
        float inv = 1.0f / l;
        const float* p = mA + sub * 2048;
        long obase = ((long)(b * LSEQ + qb + qc)) * DM + h * 64;
#pragma unroll
        for (int dt = 0; dt < 2; ++dt)
#pragma unroll
            for (int rg = 0; rg < 4; ++rg) {
                half4 o;
#pragma unroll
                for (int e = 0; e < 4; ++e) {
                    int r = 4 * rg + e;
                    float Ov = acc[dt][r] * e0 + p[(dt * 16 + r) * 64 + lane] * e1;
                    o[e] = (half_t)(Ov * inv);
                }
                *(half4*)(AO + obase + dt * 32 + 8 * rg + 4 * hi) = o;
            }
    }
}

// ---------- launch ----------
extern "C" void kernel_launch(void* const* d_in, const int* in_sizes, int n_in,
                              void* d_out, int out_size, void* d_ws, size_t ws_size,
                              hipStream_t stream) {
    const float* q  = (const float*)d_in[0];
    const float* k  = (const float*)d_in[1];
    const float* v  = (const float*)d_in[2];
    const float* wq = (const float*)d_in[4];
    const float* bq = (const float*)d_in[5];
    const float* wk = (const float*)d_in[6];
    const float* bk = (const float*)d_in[7];
    const float* wv = (const float*)d_in[8];
    const float* bv = (const float*)d_in[9];
    const float* wo = (const float*)d_in[10];
    const float* bo = (const float*)d_in[11];

    uint8_t* wsb = (uint8_t*)d_ws;
    half_t* XH = (half_t*)wsb;                       // 3 x 4194304 halfs
    half_t* WH = XH + 12582912L;                     // 4 x 1048576 halfs
    float*  COS = (float*)(wsb + 33554432L);         // [32][2048] f32
    float*  SIN = (float*)(wsb + 33816576L);
    half_t* QF = (half_t*)(wsb + 34078720L);         // fragment-packed Q
    half_t* KF = (half_t*)(wsb + 42467328L);         // fragment-packed K
    half_t* VF = (half_t*)(wsb + 50855936L);         // fragment-packed V
    half_t* AO = (half_t*)(wsb + 59244544L);         // [4096][1024] f16

    cvt_kernel<<<16640, 256, 0, stream>>>(q, k, v, wq, wk, wv, wo, XH, COS, SIN);

    qkv_gemm<<<dim3(8, 32, 3), 512, 0, stream>>>(XH, WH, bq, bk, bv, QF, KF, VF, COS, SIN);

    attn_k<<<512, 512, 0, stream>>>(QF, KF, VF, AO);

    out_gemm<<<dim3(16, 32), 512, 0, stream>>>(AO, WH + 3145728L, bo, (float*)d_out);
}

// Round 24
// 116.176 us; speedup vs baseline: 1.0059x; 1.0059x over previous
//
#include <hip/hip_runtime.h>
#include <cstdint>

typedef _Float16 half_t;
using half8 = __attribute__((ext_vector_type(8))) half_t;
using half4 = __attribute__((ext_vector_type(4))) half_t;
using f32x4 = __attribute__((ext_vector_type(4))) float;
using f32x16 = __attribute__((ext_vector_type(16))) float;

#define LSEQ 2048
#define DM   1024
#define NH   16
#define DK   64

// ---------- helpers ----------
__device__ inline void gload_lds16(const void* g, void* l) {
    __builtin_amdgcn_global_load_lds(
        (const __attribute__((address_space(1))) uint32_t*)g,
        (__attribute__((address_space(3))) uint32_t*)l, 16, 0, 0);
}

__device__ inline uint32_t pk2(float a, float b) {
    auto h = __builtin_amdgcn_cvt_pkrtz(a, b);   // v_cvt_pkrtz_f16_f32
    return __builtin_bit_cast(uint32_t, h);
}

__device__ inline float ex2(float x) { return __builtin_amdgcn_exp2f(x); }  // raw v_exp_f32

// ---------- 1. convert fp32 -> fp16 (q,k,v,W*) + RoPE table (fused) ----------
__global__ __launch_bounds__(256) void cvt_kernel(
    const float* __restrict__ q, const float* __restrict__ k, const float* __restrict__ v,
    const float* __restrict__ wq, const float* __restrict__ wk,
    const float* __restrict__ wv, const float* __restrict__ wo,
    half_t* __restrict__ dst, float* __restrict__ cosT, float* __restrict__ sinT)
{
    if (blockIdx.x >= 16384) {   // rope table: [d1=0..31][pos=0..2047]
        int tid = (blockIdx.x - 16384) * 256 + threadIdx.x;   // 65536
        int j = tid >> 11;
        int pos = tid & 2047;
        float invf = powf(10000.0f, -(float)j / 32.0f);
        float a = (float)pos * invf;
        cosT[tid] = cosf(a);
        sinT[tid] = sinf(a);
        return;
    }
    long tid = (long)blockIdx.x * 256 + threadIdx.x;
    long e = tid * 4;
    const float* src;
    long off;
    if (e < 12582912L) {
        int a = (int)(e >> 22);
        src = (a == 0) ? q : (a == 1) ? k : v;
        off = e & 4194303L;
    } else {
        long ew = e - 12582912L;
        int w = (int)(ew >> 20);
        src = (w == 0) ? wq : (w == 1) ? wk : (w == 2) ? wv : wo;
        off = ew & 1048575L;
    }
    float4 x = *(const float4*)(src + off);
    half4 o;
    o[0] = (half_t)x.x; o[1] = (half_t)x.y; o[2] = (half_t)x.z; o[3] = (half_t)x.w;
    *(half4*)(dst + e) = o;
}

// ---------- 3a. fused QKV projection GEMM, 8 waves, chunk-swizzled LDS ----------
__global__ __launch_bounds__(512, 6) void qkv_gemm(
    const half_t* __restrict__ XH, const half_t* __restrict__ WH,
    const float* __restrict__ bq, const float* __restrict__ bk, const float* __restrict__ bv,
    half_t* __restrict__ QF, half_t* __restrict__ KF, half_t* __restrict__ VF,
    const float* __restrict__ cosT, const float* __restrict__ sinT)
{
    __shared__ alignas(16) unsigned short sA[2][128 * 32];
    __shared__ alignas(16) unsigned short sB[2][128 * 32];
    const int mode = blockIdx.z;
    const half_t* A  = XH + (long)mode * 4194304L;
    const half_t* Bw = WH + (long)mode * 1048576L;
    const float* bias = (mode == 0) ? bq : (mode == 1) ? bk : bv;

    const int tid = threadIdx.x;
    const int lane = tid & 63, wid = tid >> 6;      // 0..7
    const int g = lane >> 4, c = lane & 15;
    const int wr = wid >> 1, wc = wid & 1;          // 4 x 2 wave grid
    const int row0 = blockIdx.y * 128, col0 = blockIdx.x * 128;

    f32x4 acc[2][4] = {};
    const int srow = lane >> 2;
    const int scol = ((lane & 3) ^ ((lane >> 3) & 3)) * 8;   // inverse-swizzled source chunk
    const int kx   = (g ^ ((c >> 1) & 3)) * 8;               // swizzled read chunk

    auto stage = [&](int buf, int k0) {
        int r = wid * 16;
        gload_lds16(A  + (long)(row0 + r + srow) * DM + k0 + scol, &sA[buf][r * 32]);
        gload_lds16(Bw + (long)(col0 + r + srow) * DM + k0 + scol, &sB[buf][r * 32]);
    };

    stage(0, 0);
    __syncthreads();
    int cur = 0;
#pragma unroll 1
    for (int k0 = 0; k0 < DM; k0 += 32) {
        if (k0 + 32 < DM) stage(cur ^ 1, k0 + 32);   // prefetch next K-tile
        half8 af[2], bf[4];
#pragma unroll
        for (int m = 0; m < 2; ++m)
            af[m] = *(const half8*)&sA[cur][(wr * 32 + m * 16 + c) * 32 + kx];
#pragma unroll
        for (int n = 0; n < 4; ++n)
            bf[n] = *(const half8*)&sB[cur][(wc * 64 + n * 16 + c) * 32 + kx];
#pragma unroll
        for (int m = 0; m < 2; ++m)
#pragma unroll
            for (int n = 0; n < 4; ++n)
                acc[m][n] = __builtin_amdgcn_mfma_f32_16x16x32_f16(af[m], bf[n], acc[m][n], 0, 0, 0);
        __syncthreads();
        cur ^= 1;
    }

    if (mode == 2) {
        const int h = blockIdx.x * 2 + wc;
#pragma unroll
        for (int n = 0; n < 4; ++n) {
            int col = col0 + wc * 64 + n * 16 + c;
            int d = n * 16 + c;
            float bvv = bias[col];
#pragma unroll
            for (int m = 0; m < 2; ++m) {
                int row = row0 + wr * 32 + m * 16 + g * 4;   // +r, r=0..3
                int b = row >> 11, pos = row & 2047;
                int bh = b * NH + h;
                long idx = (((((long)bh * 32 + (pos >> 6)) * 2 + (d >> 5)) * 4
                             + ((pos >> 4) & 3)) * 64
                            + (((pos >> 3) & 1) * 32 + (d & 31))) * 8 + (pos & 7);
                half4 o;
#pragma unroll
                for (int r = 0; r < 4; ++r) o[r] = (half_t)(acc[m][n][r] + bvv);
                *(half4*)(VF + idx) = o;
            }
        }
    } else {
        const float SC = (mode == 0) ? 0.125f * 1.44269504f : 1.0f;
        half_t* OF = (mode == 0) ? QF : KF;
#pragma unroll
        for (int np = 0; np < 2; ++np) {
            int col1 = col0 + wc * 64 + np * 16 + c;
            int h = col1 >> 6;
            int d1 = np * 16 + c;          // 0..31
            float b1 = bias[col1], b2 = bias[col1 + 32];
            const float* Cp = cosT + d1 * 2048;
            const float* Sp = sinT + d1 * 2048;
#pragma unroll
            for (int m = 0; m < 2; ++m) {
                int row = row0 + wr * 32 + m * 16 + g * 4;
                int pos0 = row & 2047;
                float4 cv4 = *(const float4*)(Cp + pos0);
                float4 sv4 = *(const float4*)(Sp + pos0);
#pragma unroll
                for (int r = 0; r < 4; ++r) {
                    int pos = pos0 + r;
                    int b = (row + r) >> 11;
                    int bh = b * NH + h;
                    float cv = ((const float*)&cv4)[r];
                    float sv = ((const float*)&sv4)[r];
                    float x1 = acc[m][np][r] + b1;
                    float x2 = acc[m][np + 2][r] + b2;
                    long kbase = ((long)(bh * 64 + (pos >> 5)) * 4) * 512
                               + ((c >> 3) * 32 + (pos & 31)) * 8 + (c & 7);
                    OF[kbase + (long)np * 512]       = (half_t)((x1 * cv - x2 * sv) * SC);
                    OF[kbase + (long)(np + 2) * 512] = (half_t)((x2 * cv + x1 * sv) * SC);
                }
            }
        }
    }
}

// ---------- 3b. output projection GEMM: 128x64 tiles, 512 blocks, 8 waves ----------
__global__ __launch_bounds__(512, 4) void out_gemm(
    const half_t* __restrict__ A, const half_t* __restrict__ Bw,
    const float* __restrict__ bias, float* __restrict__ o32)
{
    __shared__ alignas(16) unsigned short sA[2][128 * 32];   // 16 KB
    __shared__ alignas(16) unsigned short sB[2][64 * 32];    // 8 KB
    const int tid = threadIdx.x;
    const int lane = tid & 63, wid = tid >> 6;   // 0..7
    const int g = lane >> 4, c = lane & 15;
    const int wr = wid >> 1, wc = wid & 1;       // 4 x 2 wave grid, wave tile 32x32
    const int row0 = blockIdx.y * 128, col0 = blockIdx.x * 64;

    f32x4 acc[2][2] = {};
    const int srow = lane >> 2;
    const int scol = ((lane & 3) ^ ((lane >> 3) & 3)) * 8;
    const int kx   = (g ^ ((c >> 1) & 3)) * 8;

    auto stage = [&](int buf, int k0) {
        int rA = wid * 16;
        gload_lds16(A + (long)(row0 + rA + srow) * DM + k0 + scol, &sA[buf][rA * 32]);
        if (wid < 4) {
            int rB = wid * 16;
            gload_lds16(Bw + (long)(col0 + rB + srow) * DM + k0 + scol, &sB[buf][rB * 32]);
        }
    };

    stage(0, 0);
    __syncthreads();
    int cur = 0;
#pragma unroll 1
    for (int k0 = 0; k0 < DM; k0 += 32) {
        if (k0 + 32 < DM) stage(cur ^ 1, k0 + 32);
        half8 af[2], bf[2];
#pragma unroll
        for (int m = 0; m < 2; ++m)
            af[m] = *(const half8*)&sA[cur][(wr * 32 + m * 16 + c) * 32 + kx];
#pragma unroll
        for (int n = 0; n < 2; ++n)
            bf[n] = *(const half8*)&sB[cur][(wc * 32 + n * 16 + c) * 32 + kx];
#pragma unroll
        for (int m = 0; m < 2; ++m)
#pragma unroll
            for (int n = 0; n < 2; ++n)
                acc[m][n] = __builtin_amdgcn_mfma_f32_16x16x32_f16(af[m], bf[n], acc[m][n], 0, 0, 0);
        __syncthreads();
        cur ^= 1;
    }
#pragma unroll
    for (int n = 0; n < 2; ++n) {
        int col = col0 + wc * 32 + n * 16 + c;
        float bv = bias[col];
#pragma unroll
        for (int m = 0; m < 2; ++m)
#pragma unroll
            for (int r = 0; r < 4; ++r) {
                int row = row0 + wr * 32 + m * 16 + g * 4 + r;
                o32[(long)row * DM + col] = acc[m][n][r] + bv;
            }
    }
}

// ---------- 4. causal flash attention: balanced split-K ----------
// Block = (tile t, bh), big-first; 8 waves: sub = row slice (4 x 32 rows),
// grp = key parity (even/odd 64-key blocks of the staged 128). Every wave
// computes every staged iteration -> block wall = t+1 iters, all waves busy.
// 2-way merge per row-slice through reused LDS at the end.
__global__ __launch_bounds__(512, 3) void attn_k(
    const half_t* __restrict__ QF, const half_t* __restrict__ KF,
    const half_t* __restrict__ VF, half_t* __restrict__ AO)
{
    __shared__ half_t sK[2 * 8192];   // 32 KB: 2 buf x 128 keys x 64 d
    __shared__ half_t sV[2 * 8192];   // 32 KB

    const int tid = threadIdx.x;
    const int lane = tid & 63, wid = tid >> 6;   // 0..7
    const int t  = 15 - (blockIdx.x >> 5);       // big tiles first
    const int bh = blockIdx.x & 31;
    const int qc = lane & 31, hi = lane >> 5;
    const int b = bh >> 4, h = bh & 15;
    const int lo8 = lane * 8;
    const int sub = wid & 3, grp = wid >> 2;

    const half_t* QU = QF + (long)bh * 131072;
    const half_t* KU = KF + (long)bh * 131072;
    const half_t* VU = VF + (long)bh * 131072;

    const int qb = 128 * t + 32 * sub;
    const int kend = qb + 32;                 // keys needed by this row slice

    half8 qf[4];
#pragma unroll
    for (int dc = 0; dc < 4; ++dc)
        qf[dc] = *(const half8*)(QU + (qb >> 5) * 2048 + dc * 512 + lo8);

    f32x16 acc[2] = {};
    float lp[16];
#pragma unroll
    for (int r = 0; r < 16; ++r) lp[r] = 0.0f;
    float m = -INFINITY;

    union PB { uint32_t u[4]; half8 h8; };

    auto stage = [&](int buf, int k0) {       // stage 128 keys of K and V
#pragma unroll
        for (int rr = 0; rr < 2; ++rr) {
            gload_lds16(KU + (long)k0 * 64 + rr * 4096 + wid * 512 + lo8,
                        sK + buf * 8192 + rr * 4096 + wid * 512);
            gload_lds16(VU + (long)k0 * 64 + rr * 4096 + wid * 512 + lo8,
                        sV + buf * 8192 + rr * 4096 + wid * 512);
        }
    };

    const int nit = t + 1;                    // 128-key super-iterations
    stage(0, 0);
    __syncthreads();
    int cur = 0;
#pragma unroll 1
    for (int i = 0; i < nit; ++i) {
        if (i + 1 < nit) stage(cur ^ 1, 128 * (i + 1));
        const int base = 128 * i + grp * 64;  // this wave's 64-key block
        if (base < kend) {
            const half_t* bK = sK + cur * 8192 + grp * 4096;
            const half_t* bV = sV + cur * 8192 + grp * 4096;
            half8 kf0[4], kf1[4], vf[2][4];
#pragma unroll
            for (int dc = 0; dc < 4; ++dc) {
                kf0[dc] = *(const half8*)(bK + dc * 512 + lo8);
                kf1[dc] = *(const half8*)(bK + 2048 + dc * 512 + lo8);
            }
#pragma unroll
            for (int dt = 0; dt < 2; ++dt)
#pragma unroll
                for (int kc = 0; kc < 4; ++kc)
                    vf[dt][kc] = *(const half8*)(bV + (dt * 4 + kc) * 512 + lo8);

            // ---- QK^T ----
            f32x16 s0 = {}, s1 = {};
            __builtin_amdgcn_s_setprio(1);
#pragma unroll
            for (int dc = 0; dc < 4; ++dc) s0 = __builtin_amdgcn_mfma_f32_32x32x16_f16(kf0[dc], qf[dc], s0, 0, 0, 0);
#pragma unroll
            for (int dc = 0; dc < 4; ++dc) s1 = __builtin_amdgcn_mfma_f32_32x32x16_f16(kf1[dc], qf[dc], s1, 0, 0, 0);
            __builtin_amdgcn_s_setprio(0);

            if (base + 64 >= kend) {          // block containing the diagonal
                int qg = qb + qc;
#pragma unroll
                for (int r = 0; r < 16; ++r) {
                    int crow = (r & 3) + 8 * (r >> 2) + 4 * hi;
                    if (base + crow > qg)      s0[r] = -INFINITY;
                    if (base + 32 + crow > qg) s1[r] = -INFINITY;
                }
            }

            // ---- online softmax (defer-max; deferred l cross-reduce) ----
            float mx[8];
#pragma unroll
            for (int r = 0; r < 8; ++r)
                mx[r] = fmaxf(fmaxf(s0[r], s0[8 + r]), fmaxf(s1[r], s1[8 + r]));
#pragma unroll
            for (int st = 4; st >= 1; st >>= 1)
#pragma unroll
                for (int r = 0; r < 4; ++r)
                    if (r < st) mx[r] = fmaxf(mx[r], mx[r + st]);
            float pm = fmaxf(mx[0], __shfl_xor(mx[0], 32, 64));
            if (__any(pm > m + 8.0f)) {
                float mn = fmaxf(m, pm);
                float sc = ex2(m - mn);
#pragma unroll
                for (int r = 0; r < 16; ++r) {
                    acc[0][r] *= sc; acc[1][r] *= sc; lp[r] *= sc;
                }
                m = mn;
            }
#pragma unroll
            for (int r = 0; r < 16; ++r) {
                s0[r] = ex2(s0[r] - m);
                s1[r] = ex2(s1[r] - m);
                lp[r] += s0[r] + s1[r];
            }

            // ---- pack P^T -> PV B-operand (cvt_pkrtz + permlane32_swap) ----
            uint32_t A0[8], A1[8];
#pragma unroll
            for (int i2 = 0; i2 < 8; ++i2) {
                A0[i2] = pk2(s0[2 * i2], s0[2 * i2 + 1]);
                A1[i2] = pk2(s1[2 * i2], s1[2 * i2 + 1]);
            }
            PB B00, B01, B10, B11;
            {
                auto r0 = __builtin_amdgcn_permlane32_swap(A0[0], A0[2], false, false);
                B00.u[0] = r0[0]; B00.u[2] = r0[1];
                auto r1 = __builtin_amdgcn_permlane32_swap(A0[1], A0[3], false, false);
                B00.u[1] = r1[0]; B00.u[3] = r1[1];
                auto r2 = __builtin_amdgcn_permlane32_swap(A0[4], A0[6], false, false);
                B01.u[0] = r2[0]; B01.u[2] = r2[1];
                auto r3 = __builtin_amdgcn_permlane32_swap(A0[5], A0[7], false, false);
                B01.u[1] = r3[0]; B01.u[3] = r3[1];
                auto r4 = __builtin_amdgcn_permlane32_swap(A1[0], A1[2], false, false);
                B10.u[0] = r4[0]; B10.u[2] = r4[1];
                auto r5 = __builtin_amdgcn_permlane32_swap(A1[1], A1[3], false, false);
                B10.u[1] = r5[0]; B10.u[3] = r5[1];
                auto r6 = __builtin_amdgcn_permlane32_swap(A1[4], A1[6], false, false);
                B11.u[0] = r6[0]; B11.u[2] = r6[1];
                auto r7 = __builtin_amdgcn_permlane32_swap(A1[5], A1[7], false, false);
                B11.u[1] = r7[0]; B11.u[3] = r7[1];
            }

            // ---- PV: O^T[d][q] += V^T * P ----
            __builtin_amdgcn_s_setprio(1);
#pragma unroll
            for (int dt = 0; dt < 2; ++dt) {
                acc[dt] = __builtin_amdgcn_mfma_f32_32x32x16_f16(vf[dt][0], B00.h8, acc[dt], 0, 0, 0);
                acc[dt] = __builtin_amdgcn_mfma_f32_32x32x16_f16(vf[dt][1], B01.h8, acc[dt], 0, 0, 0);
                acc[dt] = __builtin_amdgcn_mfma_f32_32x32x16_f16(vf[dt][2], B10.h8, acc[dt], 0, 0, 0);
                acc[dt] = __builtin_amdgcn_mfma_f32_32x32x16_f16(vf[dt][3], B11.h8, acc[dt], 0, 0, 0);
            }
            __builtin_amdgcn_s_setprio(0);
        }
        __syncthreads();
        cur ^= 1;
    }

    // ---- per-lane l partial ----
    float ls = lp[0];
#pragma unroll
    for (int r = 1; r < 16; ++r) ls += lp[r];

    // ---- 2-way split-K merge (grp1 -> LDS, grp0 finalizes) ----
    float* mA  = (float*)sK;    // 4 subs x 2048 f32 (32 KB)
    float* mML = (float*)sV;    // 4 subs x 128 f32
    if (grp == 1) {
        float* p = mA + sub * 2048;
#pragma unroll
        for (int dt = 0; dt < 2; ++dt)
#pragma unroll
            for (int r = 0; r < 16; ++r)
                p[(dt * 16 + r) * 64 + lane] = acc[dt][r];
        mML[sub * 128 + lane] = m;
        mML[sub * 128 + 64 + lane] = ls;
    }
    __syncthreads();
    if (grp == 0) {
        float m1  = mML[sub * 128 + lane];
        float ls1 = mML[sub * 128 + 64 + lane];
        float M = fmaxf(m, m1);
        float e0 = ex2(m - M), e1 = ex2(m1 - M);
        float lsM = ls * e0 + ls1 * e1;
        float l = lsM + __shfl_xor(lsM, 32, 64);
        float inv = 1.0f / l;
        const float* p = mA + sub * 2048;
        long obase = ((long)(b * LSEQ + qb + qc)) * DM + h * 64;
#pragma unroll
        for (int dt = 0; dt < 2; ++dt)
#pragma unroll
            for (int rg = 0; rg < 4; ++rg) {
                half4 o;
#pragma unroll
                for (int e = 0; e < 4; ++e) {
                    int r = 4 * rg + e;
                    float Ov = acc[dt][r] * e0 + p[(dt * 16 + r) * 64 + lane] * e1;
                    o[e] = (half_t)(Ov * inv);
                }
                *(half4*)(AO + obase + dt * 32 + 8 * rg + 4 * hi) = o;
            }
    }
}

// ---------- launch ----------
extern "C" void kernel_launch(void* const* d_in, const int* in_sizes, int n_in,
                              void* d_out, int out_size, void* d_ws, size_t ws_size,
                              hipStream_t stream) {
    const float* q  = (const float*)d_in[0];
    const float* k  = (const float*)d_in[1];
    const float* v  = (const float*)d_in[2];
    const float* wq = (const float*)d_in[4];
    const float* bq = (const float*)d_in[5];
    const float* wk = (const float*)d_in[6];
    const float* bk = (const float*)d_in[7];
    const float* wv = (const float*)d_in[8];
    const float* bv = (const float*)d_in[9];
    const float* wo = (const float*)d_in[10];
    const float* bo = (const float*)d_in[11];

    uint8_t* wsb = (uint8_t*)d_ws;
    half_t* XH = (half_t*)wsb;                       // 3 x 4194304 halfs
    half_t* WH = XH + 12582912L;                     // 4 x 1048576 halfs
    float*  COS = (float*)(wsb + 33554432L);         // [32][2048] f32
    float*  SIN = (float*)(wsb + 33816576L);
    half_t* QF = (half_t*)(wsb + 34078720L);         // fragment-packed Q
    half_t* KF = (half_t*)(wsb + 42467328L);         // fragment-packed K
    half_t* VF = (half_t*)(wsb + 50855936L);         // fragment-packed V
    half_t* AO = (half_t*)(wsb + 59244544L);         // [4096][1024] f16

    cvt_kernel<<<16640, 256, 0, stream>>>(q, k, v, wq, wk, wv, wo, XH, COS, SIN);

    qkv_gemm<<<dim3(8, 32, 3), 512, 0, stream>>>(XH, WH, bq, bk, bv, QF, KF, VF, COS, SIN);

    attn_k<<<512, 512, 0, stream>>>(QF, KF, VF, AO);

    out_gemm<<<dim3(16, 32), 512, 0, stream>>>(AO, WH + 3145728L, bo, (float*)d_out);
}